// Round 5
// baseline (509.871 us; speedup 1.0000x reference)
//
#include <hip/hip_runtime.h>

#define DIM_OUT 64
#define ALPHA 0.5f
#define BLOCK 256
#define NF4 (DIM_OUT / 4)   // 16 float4 per output row
#define PERSIST_BLOCKS 512  // 2 per CU (64 KB LDS each)

// Persistent-block version of the round-4 kernel. Data layout is IDENTICAL to
// the verified round-4 kernel (XOR-swizzled [256][16]-float4 LDS tile, b128
// both sides at the 8-touches/bank floor, 16-lane-per-row coalesced flush).
// What changed: 512 blocks (2/CU) grid-stride over all tiles and never
// retire. LDS hazards are fenced with raw s_barrier + explicit
// s_waitcnt lgkmcnt(0) ONLY — never vmcnt — so global stores from tile t
// remain in flight across tile t+1's compute. This removes the per-block
// store-drain + workgroup-teardown + relaunch serialization that capped
// round 4 at ~3 TB/s effective write BW (the harness fill proves 6.2 TB/s
// is reachable at 10% occupancy, so continuous store issue is all we need).
__global__ __launch_bounds__(BLOCK) void geg_kernel(const float* __restrict__ x,
                                                    float* __restrict__ out,
                                                    int n, int ntiles) {
    __shared__ float4 lds[BLOCK * NF4];   // 256*16*16B = 64 KB -> 2 blocks/CU

    const int tid = threadIdx.x;
    const int wsw = tid & 7;              // write-side swizzle key

    int tile = blockIdx.x;
    if (tile >= ntiles) return;

    // first tile's x (coalesced 1 KB per block)
    {
        const size_t row = (size_t)tile * BLOCK + tid;
        // fallthrough into loop with xv loaded
    }
    size_t row0 = (size_t)tile * BLOCK + tid;
    float xv = (row0 < (size_t)n) ? x[row0] : 0.0f;

    for (;;) {
        // ---- compute all 64 orders into LDS, 16 swizzled b128 writes ----
        float prev2 = 1.0f;               // C_0
        float prev  = 2.0f * ALPHA * xv;  // C_1
        #pragma unroll
        for (int s = 0; s < NF4; ++s) {
            float v0, v1, v2, v3;
            #pragma unroll
            for (int k = 0; k < 4; ++k) {
                const int ord = s * 4 + k + 1;     // order 1..64
                float ci;
                if (ord == 1) {
                    ci = prev;                     // C_1 already computed
                } else {
                    const float a   = (2.0f * (float)ord - 2.0f + 2.0f * ALPHA);
                    const float b   = (-(float)ord + 2.0f - 2.0f * ALPHA);
                    const float inv = 1.0f / (float)ord;
                    ci = (a * xv * prev + b * prev2) * inv;  // same assoc as verified kernels
                    prev2 = prev;
                    prev  = ci;
                }
                if (k == 0) v0 = ci; else if (k == 1) v1 = ci;
                else if (k == 2) v2 = ci; else v3 = ci;
            }
            lds[tid * NF4 + (s ^ wsw)] = make_float4(v0, v1, v2, v3);
        }

        // ---- prefetch next tile's x; latency hides under the flush ----
        const int next_tile = tile + (int)gridDim.x;   // block-uniform
        float xv_next = 0.0f;
        if (next_tile < ntiles) {
            const size_t nrow = (size_t)next_tile * BLOCK + tid;
            xv_next = (nrow < (size_t)n) ? x[nrow] : 0.0f;
        }

        // ds_writes visible to all waves; do NOT drain stores (no vmcnt).
        asm volatile("s_waitcnt lgkmcnt(0)" ::: "memory");
        __builtin_amdgcn_s_barrier();
        __builtin_amdgcn_sched_barrier(0);

        // ---- flush: 256 rows x 16 f4; 16 consecutive lanes = one 256B row ----
        const size_t base_row = (size_t)tile * BLOCK;
        #pragma unroll
        for (int j = 0; j < NF4; ++j) {
            const int f  = j * BLOCK + tid;
            const int r  = f >> 4;
            const int c4 = f & 15;
            const size_t grow = base_row + r;
            if (grow < (size_t)n) {
                float4 v = lds[r * NF4 + (c4 ^ (r & 7))];
                *(float4*)(out + grow * DIM_OUT + c4 * 4) = v;
            }
        }

        if (next_tile >= ntiles) break;   // stores drain at dispatch end

        // flush ds_reads done in all waves before next compute overwrites LDS;
        // again lgkm only — stores from this tile stay in flight.
        asm volatile("s_waitcnt lgkmcnt(0)" ::: "memory");
        __builtin_amdgcn_s_barrier();
        __builtin_amdgcn_sched_barrier(0);

        tile = next_tile;
        xv = xv_next;    // compiler inserts a counted vmcnt wait (not 0) here
    }
}

extern "C" void kernel_launch(void* const* d_in, const int* in_sizes, int n_in,
                              void* d_out, int out_size, void* d_ws, size_t ws_size,
                              hipStream_t stream) {
    const float* x = (const float*)d_in[0];
    float* out = (float*)d_out;
    int n = in_sizes[0];   // 2,000,000 rows (x is [n,1])

    const int ntiles = (n + BLOCK - 1) / BLOCK;
    const int grid = ntiles < PERSIST_BLOCKS ? ntiles : PERSIST_BLOCKS;
    geg_kernel<<<grid, BLOCK, 0, stream>>>(x, out, n, ntiles);
}

// Round 6
// 501.736 us; speedup vs baseline: 1.0162x; 1.0162x over previous
//
#include <hip/hip_runtime.h>

#define DIM_OUT 64
#define ALPHA 0.5f
#define WAVE 64
#define NF4 (DIM_OUT / 4)   // 16 float4 per output row

// Barrier-free wave-local transpose. Each block is ONE wave (64 threads) that
// owns a private 16 KB LDS tile [64 rows][16 float4] and never executes a
// barrier: a wave is lockstep, and same-wave DS ops are in-order, so the
// write->read hazard needs only one s_waitcnt lgkmcnt(0). This removes the
// block-wide barrier phase-lock that kept r2/r4/r5 all at ~173 us (~3 TB/s):
// with all waves barrier-aligned, stores issued only in burst phases and the
// per-CU write queue ran dry during compute phases (fill proves 6.2 TB/s
// needs only continuous issue at 10% occupancy). Here 10 waves/CU (16 KB
// each) free-run and de-phase, giving a continuous fill-like store stream.
//
// Layout (identical math to verified r4): phys_c4 = c4 ^ (row & 7).
//   write side (thread l = row l, slot s): bank-quad = (s^(l&7))&7 -> 8
//   lanes/quad (b128 floor). read side (iter j: r = j*4+(l>>4), c4 = l&15):
//   quad = (c4^(r&7))&7 -> 8 lanes/quad. Flush: 16 consecutive lanes cover
//   one full 256B row; each wave store = 1 KB contiguous, full 64B lines.
__global__ __launch_bounds__(WAVE) void geg_kernel(const float* __restrict__ x,
                                                   float* __restrict__ out,
                                                   int n) {
    __shared__ float4 lds[WAVE * NF4];   // 16 KB, private to this 1-wave block

    const int l = threadIdx.x;           // lane 0..63
    const size_t base_row = (size_t)blockIdx.x * WAVE;
    const size_t row = base_row + l;

    const float xv = (row < (size_t)n) ? x[row] : 0.0f;

    float prev2 = 1.0f;               // C_0
    float prev  = 2.0f * ALPHA * xv;  // C_1

    const int wsw = l & 7;            // write-side swizzle key

    // ---- compute all 64 orders, 4 at a time, one swizzled b128 write each ----
    #pragma unroll
    for (int s = 0; s < NF4; ++s) {
        float v0, v1, v2, v3;
        #pragma unroll
        for (int k = 0; k < 4; ++k) {
            const int ord = s * 4 + k + 1;     // order 1..64
            float ci;
            if (ord == 1) {
                ci = prev;                     // C_1 already computed
            } else {
                const float a   = (2.0f * (float)ord - 2.0f + 2.0f * ALPHA);
                const float b   = (-(float)ord + 2.0f - 2.0f * ALPHA);
                const float inv = 1.0f / (float)ord;
                ci = (a * xv * prev + b * prev2) * inv;  // same assoc as verified kernels
                prev2 = prev;
                prev  = ci;
            }
            if (k == 0) v0 = ci; else if (k == 1) v1 = ci;
            else if (k == 2) v2 = ci; else v3 = ci;
        }
        lds[l * NF4 + (s ^ wsw)] = make_float4(v0, v1, v2, v3);
    }

    // Wave-local W->R fence: no barrier, no vmem outstanding at this point,
    // so this costs only the tail latency of the last ds_write.
    asm volatile("s_waitcnt lgkmcnt(0)" ::: "memory");

    // ---- flush: 64 rows x 16 f4; iter j stores rows j*4..j*4+3 (1 KB contig) ----
    #pragma unroll
    for (int j = 0; j < NF4; ++j) {
        const int r  = j * 4 + (l >> 4);   // row within tile
        const int c4 = l & 15;             // f4 column
        const size_t grow = base_row + r;
        if (grow < (size_t)n) {
            float4 v = lds[r * NF4 + (c4 ^ (r & 7))];
            *(float4*)(out + grow * DIM_OUT + c4 * 4) = v;
        }
    }
    // stores drain while other de-phased waves keep the pipe fed
}

extern "C" void kernel_launch(void* const* d_in, const int* in_sizes, int n_in,
                              void* d_out, int out_size, void* d_ws, size_t ws_size,
                              hipStream_t stream) {
    const float* x = (const float*)d_in[0];
    float* out = (float*)d_out;
    int n = in_sizes[0];   // 2,000,000 rows (x is [n,1]); 2M/64 = 31250 exact

    const int grid = (n + WAVE - 1) / WAVE;
    geg_kernel<<<grid, WAVE, 0, stream>>>(x, out, n);
}